// Round 2
// baseline (10406.253 us; speedup 1.0000x reference)
//
#include <hip/hip_runtime.h>
#include <stdint.h>

using short8 = __attribute__((ext_vector_type(8))) short;
using f32x4  = __attribute__((ext_vector_type(4))) float;

#define DEV static __device__ __forceinline__

DEV unsigned short f2bf(float f){
  unsigned u = __builtin_bit_cast(unsigned, f);
  u = (u + 0x7FFFu + ((u >> 16) & 1u)) >> 16;
  return (unsigned short)u;
}
DEV float sigm(float x){
  float e = __builtin_amdgcn_exp2f(-1.4426950408889634f * x);
  return __builtin_amdgcn_rcpf(1.0f + e);
}
DEV float tanh_(float x){
  float e = __builtin_amdgcn_exp2f(2.885390081777927f * x); // exp(2x)
  return 1.0f - 2.0f * __builtin_amdgcn_rcpf(e + 1.0f);
}

// ---------------- aux kernels ----------------

__global__ void k_f32_to_bf16(const float* __restrict__ in, unsigned short* __restrict__ out, int n){
  int stride = gridDim.x * blockDim.x * 4;
  for (int i = (blockIdx.x * blockDim.x + threadIdx.x) * 4; i < n; i += stride){
    float4 v = *(const float4*)(in + i);
    ushort4 o4;
    o4.x = f2bf(v.x); o4.y = f2bf(v.y); o4.z = f2bf(v.z); o4.w = f2bf(v.w);
    *(ushort4*)(out + i) = o4;
  }
}

__global__ void k_add_bf16(const float* __restrict__ a, const float* __restrict__ b,
                           unsigned short* __restrict__ out, int n){
  int stride = gridDim.x * blockDim.x * 4;
  for (int i = (blockIdx.x * blockDim.x + threadIdx.x) * 4; i < n; i += stride){
    float4 va = *(const float4*)(a + i);
    float4 vb = *(const float4*)(b + i);
    ushort4 o4;
    o4.x = f2bf(va.x + vb.x); o4.y = f2bf(va.y + vb.y);
    o4.z = f2bf(va.z + vb.z); o4.w = f2bf(va.w + vb.w);
    *(ushort4*)(out + i) = o4;
  }
}

__global__ void k_add_f32(float* __restrict__ o, const float* __restrict__ b, int n){
  int stride = gridDim.x * blockDim.x * 4;
  for (int i = (blockIdx.x * blockDim.x + threadIdx.x) * 4; i < n; i += stride){
    float4 vo = *(const float4*)(o + i);
    float4 vb = *(const float4*)(b + i);
    vo.x += vb.x; vo.y += vb.y; vo.z += vb.z; vo.w += vb.w;
    *(float4*)(o + i) = vo;
  }
}

// Pack [k; r] (f32, [K, 4U] each, K split KX|U) into per-(dir,wg,wave,ktile,ntile)
// MFMA B-fragment order: idx = ((((wg*4+w)*6+kt)*4+nt)*64+lane)*8+j
__global__ void k_pack(const float* __restrict__ k0, const float* __restrict__ r0,
                       const float* __restrict__ k1, const float* __restrict__ r1,
                       unsigned short* __restrict__ out, int E, int KX, int U){
  int n = 2 * E;
  int stride = gridDim.x * blockDim.x;
  for (int i = blockIdx.x * blockDim.x + threadIdx.x; i < n; i += stride){
    int d = i / E, r = i % E;
    const float* Km = d ? k1 : k0;
    const float* Rm = d ? r1 : r0;
    int j    = r & 7;  int q = r >> 3;
    int lane = q & 63; q >>= 6;
    int nt   = q & 3;  q >>= 2;
    int kt   = q % 6;  q /= 6;
    int w    = q & 3;  int wg = q >> 2;
    int k    = (w*6 + kt)*32 + ((lane >> 4) << 3) + j;
    int col  = nt * U + wg*16 + (lane & 15);   // gate-major global column
    float v  = (k < KX) ? Km[(size_t)k * (4*U) + col]
                        : Rm[(size_t)(k - KX) * (4*U) + col];
    out[i] = f2bf(v);
  }
}

// ---------------- persistent recurrence kernel ----------------
// One bidirectional LSTM layer. grid = 2*WGS blocks (fwd group, bwd group).
// Cross-WG h exchange: plain stores -> syncthreads (per-wave vmcnt drain, all
// h in XCD L2) -> tid0 RELEASE flag store (waitcnt + buffer_wbl2 + store, NO
// L2 invalidate anywhere) -> readers use agent-scope relaxed atomic loads
// (sc0 sc1: bypass L1/L2, read coherence point). x/B stay warm in L2.
template<int KX, int U, int WGS>
__global__ __launch_bounds__(256, 1)
void lstm_rec(const unsigned short* __restrict__ xab,    // [64][512][KX] bf16
              const unsigned short* __restrict__ packedB,// per-dir packed [k;r]
              const float* __restrict__ bias_f,
              const float* __restrict__ bias_b,
              const int*   __restrict__ sizes,
              unsigned short* __restrict__ hbuf,         // [2 dirs][2][64][U] bf16
              unsigned int*  __restrict__ flags,         // [2 dirs][WGS*32]
              float* __restrict__ out_f,                 // [64][512][U]
              float* __restrict__ out_b)
{
  constexpr int KT  = (KX + U) / 32;   // 24
  constexpr int KTW = KT / 4;          // 6 ktiles per wave
  constexpr int T   = 512;

  const int tid  = threadIdx.x;
  const int w    = tid >> 6;
  const int lane = tid & 63;
  const int dir  = (blockIdx.x >= WGS) ? 1 : 0;
  const int wg   = dir ? (int)blockIdx.x - WGS : (int)blockIdx.x;

  const unsigned short* pB = packedB + (size_t)dir * ((size_t)WGS*4*KTW*4*512)
                                     + (size_t)((wg*4 + w)*KTW)*4*512;
  unsigned short* hb = hbuf + (size_t)dir * (2*64*U);
  unsigned int*   flg = flags + dir * (WGS*32);
  const float* bias = dir ? bias_b : bias_f;
  float* outp       = dir ? out_b : out_f;

  // preload B fragments (step-invariant) into registers: 96 VGPRs
  short8 bfr[KTW][4];
  #pragma unroll
  for (int kt = 0; kt < KTW; ++kt)
    #pragma unroll
    for (int nt = 0; nt < 4; ++nt)
      bfr[kt][nt] = *(const short8*)(pB + ((kt*4 + nt)*512) + lane*8);

  // gate-phase ownership: unit u_l (0..15), rows rb..rb+3
  const int u_l = tid & 15;
  const int rb  = (tid >> 4) * 4;
  const int ug  = wg*16 + u_l;
  float bz[4]; int sz[4];
  #pragma unroll
  for (int g = 0; g < 4; ++g) bz[g] = bias[g*U + ug];
  #pragma unroll
  for (int r = 0; r < 4; ++r) sz[r] = sizes[rb + r];
  float c[4]    = {0.f,0.f,0.f,0.f};
  float hreg[4] = {0.f,0.f,0.f,0.f};

  // [wave][zcol 64][row 64 + pad] -> both write (D-frag) and read (gate) are b128
  __shared__ float part[4][64][68];

  const int arow = lane & 15;         // A-frag row / D-frag col within tile
  const int kgrp = (lane >> 4) * 8;   // A-frag k offset within ktile
  const int rquad = (lane >> 4) * 4;  // D-frag row base

  for (int s = 0; s < T; ++s){
    const int t   = dir ? (T - 1 - s) : s;
    const int par = s & 1;

    f32x4 acc[4][4];
    #pragma unroll
    for (int mt = 0; mt < 4; ++mt)
      #pragma unroll
      for (int nt = 0; nt < 4; ++nt)
        acc[mt][nt] = (f32x4){0.f, 0.f, 0.f, 0.f};

    #pragma unroll
    for (int kt = 0; kt < KTW; ++kt){
      const int kg = (w*KTW + kt) * 32;
      #pragma unroll
      for (int mt = 0; mt < 4; ++mt){
        const int row = mt*16 + arow;   // batch row
        short8 a;
        if (kg < KX){
          a = *(const short8*)(xab + ((size_t)(row*T + t))*KX + (kg + kgrp));
        } else {
          const unsigned long long* hp = (const unsigned long long*)
              (hb + (size_t)par*64*U + (size_t)row*U + (kg - KX + kgrp));
          ulonglong2 u;
          u.x = __hip_atomic_load(hp,     __ATOMIC_RELAXED, __HIP_MEMORY_SCOPE_AGENT);
          u.y = __hip_atomic_load(hp + 1, __ATOMIC_RELAXED, __HIP_MEMORY_SCOPE_AGENT);
          a = __builtin_bit_cast(short8, u);
        }
        #pragma unroll
        for (int nt = 0; nt < 4; ++nt)
          acc[mt][nt] = __builtin_amdgcn_mfma_f32_16x16x32_bf16(a, bfr[kt][nt], acc[mt][nt], 0, 0, 0);
      }
    }

    // D-frag: col = lane&15 (zcol), rows = rquad..rquad+3 -> contiguous b128
    #pragma unroll
    for (int mt = 0; mt < 4; ++mt)
      #pragma unroll
      for (int nt = 0; nt < 4; ++nt)
        *(f32x4*)&part[w][nt*16 + arow][mt*16 + rquad] = acc[mt][nt];

    __syncthreads();

    // gate phase: reduce 4 wave partials; thread owns unit u_l, rows rb..rb+3
    f32x4 zg[4];
    #pragma unroll
    for (int g = 0; g < 4; ++g){
      const int cb = g*16 + u_l;
      f32x4 v = *(const f32x4*)&part[0][cb][rb];
      #pragma unroll
      for (int ww = 1; ww < 4; ++ww)
        v += *(const f32x4*)&part[ww][cb][rb];
      zg[g] = v;
    }

    #pragma unroll
    for (int r = 0; r < 4; ++r){
      float ig = sigm (zg[0][r] + bz[0]);
      float fg = sigm (zg[1][r] + bz[1]);
      float gg = tanh_(zg[2][r] + bz[2]);
      float og = sigm (zg[3][r] + bz[3]);
      float cn = fg * c[r] + ig * gg;
      float hn = og * tanh_(cn);
      bool m  = (t < sz[r]);
      c[r] = m ? cn : c[r];
      float h = m ? hn : hreg[r];
      hreg[r] = h;
      hb[(size_t)(par ^ 1)*64*U + (size_t)(rb + r)*U + ug] = f2bf(h);  // plain store
      outp[((size_t)(rb + r)*T + t)*U + ug] = h;
    }

    if (s != T - 1){
      __syncthreads();  // each wave drains its vmcnt: all h stores are in XCD L2
      if (tid == 0){
        // release: s_waitcnt + buffer_wbl2 (flush dirty h/out lines to LLC) + flag store
        __hip_atomic_store(&flg[wg*32], (unsigned)(s + 1),
                           __ATOMIC_RELEASE, __HIP_MEMORY_SCOPE_AGENT);
      }
      if (tid < 64){
        const unsigned tgt = (unsigned)(s + 1);
        for (;;){
          unsigned v = (lane < WGS)
            ? __hip_atomic_load(&flg[lane*32], __ATOMIC_RELAXED, __HIP_MEMORY_SCOPE_AGENT)
            : tgt;
          if (__all(v >= tgt)) break;
          __builtin_amdgcn_s_sleep(1);
        }
      }
      __syncthreads();
    }
  }
}

// ---------------- launch ----------------

extern "C" void kernel_launch(void* const* d_in, const int* in_sizes, int n_in,
                              void* d_out, int out_size, void* d_ws, size_t ws_size,
                              hipStream_t stream){
  const float* x      = (const float*)d_in[0];
  const int*   sizes  = (const int*)  d_in[1];
  const float* enc_kf = (const float*)d_in[2];
  const float* enc_rf = (const float*)d_in[3];
  const float* enc_bf = (const float*)d_in[4];
  const float* enc_kb = (const float*)d_in[5];
  const float* enc_rb = (const float*)d_in[6];
  const float* enc_bb = (const float*)d_in[7];
  const float* dec_kf = (const float*)d_in[8];
  const float* dec_rf = (const float*)d_in[9];
  const float* dec_bf = (const float*)d_in[10];
  const float* dec_kb = (const float*)d_in[11];
  const float* dec_rb = (const float*)d_in[12];
  const float* dec_bb = (const float*)d_in[13];
  float* out = (float*)d_out;
  char*  ws  = (char*)d_ws;

  const size_t o_xbf   = 0;                        // 33,554,432  x as bf16 [64][512][512]
  const size_t o_esum  = o_xbf   + 33554432ull;    // 16,777,216  enc fwd+bwd sum bf16
  const size_t o_pBe   = o_esum  + 16777216ull;    //  3,145,728  packed enc [k;r]
  const size_t o_pBd   = o_pBe   + 3145728ull;     //  6,291,456  packed dec [k;r]
  const size_t o_hfe   = o_pBd   + 6291456ull;     // 33,554,432  enc fwd h f32
  const size_t o_hbe   = o_hfe   + 33554432ull;    // 33,554,432  enc bwd h f32
  const size_t o_hbd   = o_hbe   + 33554432ull;    // 67,108,864  dec bwd h f32
  const size_t o_hbufe = o_hbd   + 67108864ull;    //    131,072  enc h exchange
  const size_t o_hbufd = o_hbufe + 131072ull;      //    262,144  dec h exchange
  const size_t o_flge  = o_hbufd + 262144ull;      //      4,096  enc flags
  const size_t o_flgd  = o_flge  + 4096ull;        //      8,192  dec flags
  const size_t total   = o_flgd  + 8192ull;
  if (ws_size < total) return;

  unsigned short* xbf   = (unsigned short*)(ws + o_xbf);
  unsigned short* esum  = (unsigned short*)(ws + o_esum);
  unsigned short* pBe   = (unsigned short*)(ws + o_pBe);
  unsigned short* pBd   = (unsigned short*)(ws + o_pBd);
  float*          hfe   = (float*)(ws + o_hfe);
  float*          hbe   = (float*)(ws + o_hbe);
  float*          hbd   = (float*)(ws + o_hbd);
  unsigned short* hbufe = (unsigned short*)(ws + o_hbufe);
  unsigned short* hbufd = (unsigned short*)(ws + o_hbufd);
  unsigned int*   flge  = (unsigned int*)(ws + o_flge);
  unsigned int*   flgd  = (unsigned int*)(ws + o_flgd);

  // zero h exchange buffers + flags (every call -> deterministic replays)
  hipMemsetAsync(ws + o_hbufe, 0, 131072ull + 262144ull + 4096ull + 8192ull, stream);

  // x -> bf16
  k_f32_to_bf16<<<2048, 256, 0, stream>>>(x, xbf, 64*512*512);

  // pack weights
  k_pack<<<2048, 256, 0, stream>>>(enc_kf, enc_rf, enc_kb, enc_rb, pBe, 786432, 512, 256);
  k_pack<<<2048, 256, 0, stream>>>(dec_kf, dec_rf, dec_kb, dec_rb, pBd, 1572864, 256, 512);

  // encoder bilstm (fwd group 16 WGs + bwd group 16 WGs)
  lstm_rec<512, 256, 16><<<32, 256, 0, stream>>>(xbf, pBe, enc_bf, enc_bb, sizes,
                                                 hbufe, flge, hfe, hbe);
  // enc_sum = bf16(hf + hb)
  k_add_bf16<<<2048, 256, 0, stream>>>(hfe, hbe, esum, 64*512*256);

  // decoder bilstm: fwd writes d_out directly, bwd to ws
  lstm_rec<256, 512, 32><<<64, 256, 0, stream>>>(esum, pBd, dec_bf, dec_bb, sizes,
                                                 hbufd, flgd, out, hbd);
  // d_out += dec bwd
  k_add_f32<<<2048, 256, 0, stream>>>(out, hbd, 64*512*512);
}

// Round 4
// 8738.731 us; speedup vs baseline: 1.1908x; 1.1908x over previous
//
#include <hip/hip_runtime.h>
#include <stdint.h>

using short8 = __attribute__((ext_vector_type(8))) short;
using f32x4  = __attribute__((ext_vector_type(4))) float;

#define DEV static __device__ __forceinline__

DEV unsigned short f2bf(float f){
  unsigned u = __builtin_bit_cast(unsigned, f);
  u = (u + 0x7FFFu + ((u >> 16) & 1u)) >> 16;
  return (unsigned short)u;
}
DEV float sigm(float x){
  float e = __builtin_amdgcn_exp2f(-1.4426950408889634f * x);
  return __builtin_amdgcn_rcpf(1.0f + e);
}
DEV float tanh_(float x){
  float e = __builtin_amdgcn_exp2f(2.885390081777927f * x); // exp(2x)
  return 1.0f - 2.0f * __builtin_amdgcn_rcpf(e + 1.0f);
}

// ---------------- aux kernels ----------------

__global__ void k_f32_to_bf16(const float* __restrict__ in, unsigned short* __restrict__ out, int n){
  int stride = gridDim.x * blockDim.x * 4;
  for (int i = (blockIdx.x * blockDim.x + threadIdx.x) * 4; i < n; i += stride){
    float4 v = *(const float4*)(in + i);
    ushort4 o4;
    o4.x = f2bf(v.x); o4.y = f2bf(v.y); o4.z = f2bf(v.z); o4.w = f2bf(v.w);
    *(ushort4*)(out + i) = o4;
  }
}

__global__ void k_add_bf16(const float* __restrict__ a, const float* __restrict__ b,
                           unsigned short* __restrict__ out, int n){
  int stride = gridDim.x * blockDim.x * 4;
  for (int i = (blockIdx.x * blockDim.x + threadIdx.x) * 4; i < n; i += stride){
    float4 va = *(const float4*)(a + i);
    float4 vb = *(const float4*)(b + i);
    ushort4 o4;
    o4.x = f2bf(va.x + vb.x); o4.y = f2bf(va.y + vb.y);
    o4.z = f2bf(va.z + vb.z); o4.w = f2bf(va.w + vb.w);
    *(ushort4*)(out + i) = o4;
  }
}

__global__ void k_add_f32(float* __restrict__ o, const float* __restrict__ b, int n){
  int stride = gridDim.x * blockDim.x * 4;
  for (int i = (blockIdx.x * blockDim.x + threadIdx.x) * 4; i < n; i += stride){
    float4 vo = *(const float4*)(o + i);
    float4 vb = *(const float4*)(b + i);
    vo.x += vb.x; vo.y += vb.y; vo.z += vb.z; vo.w += vb.w;
    *(float4*)(o + i) = vo;
  }
}

// Pack [k; r] (f32, [K, 4U] each, K split KX|U) into per-(dir,wg,wave,ktile,ntile)
// MFMA B-fragment order: idx = ((((wg*4+w)*6+kt)*4+nt)*64+lane)*8+j
__global__ void k_pack(const float* __restrict__ k0, const float* __restrict__ r0,
                       const float* __restrict__ k1, const float* __restrict__ r1,
                       unsigned short* __restrict__ out, int E, int KX, int U){
  int n = 2 * E;
  int stride = gridDim.x * blockDim.x;
  for (int i = blockIdx.x * blockDim.x + threadIdx.x; i < n; i += stride){
    int d = i / E, r = i % E;
    const float* Km = d ? k1 : k0;
    const float* Rm = d ? r1 : r0;
    int j    = r & 7;  int q = r >> 3;
    int lane = q & 63; q >>= 6;
    int nt   = q & 3;  q >>= 2;
    int kt   = q % 6;  q /= 6;
    int w    = q & 3;  int wg = q >> 2;
    int k    = (w*6 + kt)*32 + ((lane >> 4) << 3) + j;
    int col  = nt * U + wg*16 + (lane & 15);   // gate-major global column
    float v  = (k < KX) ? Km[(size_t)k * (4*U) + col]
                        : Rm[(size_t)(k - KX) * (4*U) + col];
    out[i] = f2bf(v);
  }
}

// ---------------- persistent recurrence kernel ----------------
// One bidirectional LSTM layer. grid = 2*WGS blocks (fwd group, bwd group).
// Cross-WG h exchange: ALL exchange traffic (h + flags) uses relaxed
// AGENT-scope atomics. Atomic stores are write-through to the device
// coherence point (no wbl2 needed); atomic loads read the coherence point
// (no invalidate needed). Zero cache-maintenance ops -> x/weights/out stay
// ordinary cached accesses, L2 warm across all 512 steps.
// Ordering: h atomic stores -> __syncthreads (drains vmcnt in every wave)
// -> tid0 relaxed flag store -> readers poll flag, then atomic-load h.
template<int KX, int U, int WGS>
__global__ __launch_bounds__(256, 1)
void lstm_rec(const unsigned short* __restrict__ xab,    // [64][512][KX] bf16
              const unsigned short* __restrict__ packedB,
              const float* __restrict__ bias_f,
              const float* __restrict__ bias_b,
              const int*   __restrict__ sizes,
              unsigned short* __restrict__ hbuf,         // [2 dirs][2][64][U] bf16
              unsigned int*  __restrict__ flags,         // [2 dirs][WGS*32]
              float* __restrict__ out_f,                 // [64][512][U]
              float* __restrict__ out_b)
{
  constexpr int KT  = (KX + U) / 32;   // 24
  constexpr int KTW = KT / 4;          // 6 ktiles per wave
  constexpr int T   = 512;

  const int tid  = threadIdx.x;
  const int w    = tid >> 6;
  const int lane = tid & 63;
  const int dir  = (blockIdx.x >= WGS) ? 1 : 0;
  const int wg   = dir ? (int)blockIdx.x - WGS : (int)blockIdx.x;

  const unsigned short* pB = packedB + (size_t)dir * ((size_t)WGS*4*KTW*4*512)
                                     + (size_t)((wg*4 + w)*KTW)*4*512;
  unsigned short* hb = hbuf + (size_t)dir * (2*64*U);
  unsigned int*   flg = flags + dir * (WGS*32);
  const float* bias = dir ? bias_b : bias_f;
  float* outp       = dir ? out_b : out_f;

  // preload B fragments (step-invariant) into registers: 96 VGPRs
  short8 bfr[KTW][4];
  #pragma unroll
  for (int kt = 0; kt < KTW; ++kt)
    #pragma unroll
    for (int nt = 0; nt < 4; ++nt)
      bfr[kt][nt] = *(const short8*)(pB + ((kt*4 + nt)*512) + lane*8);

  // gate-phase ownership: unit u_l (0..15), rows rb..rb+3
  const int u_l = tid & 15;
  const int rb  = (tid >> 4) * 4;
  const int ug  = wg*16 + u_l;
  float bz[4]; int sz[4];
  #pragma unroll
  for (int g = 0; g < 4; ++g) bz[g] = bias[g*U + ug];
  #pragma unroll
  for (int r = 0; r < 4; ++r) sz[r] = sizes[rb + r];
  float c[4]    = {0.f,0.f,0.f,0.f};
  float hreg[4] = {0.f,0.f,0.f,0.f};

  // [wave][zcol 64][row 64 + pad] -> both write (D-frag) and read (gate) are b128
  __shared__ float part[4][64][68];

  const int arow  = lane & 15;         // A-frag row / D-frag col within tile
  const int kgrp  = (lane >> 4) * 8;   // A-frag k offset within ktile
  const int rquad = (lane >> 4) * 4;   // D-frag row base

  for (int s = 0; s < T; ++s){
    const int t   = dir ? (T - 1 - s) : s;
    const int par = s & 1;

    f32x4 acc[4][4];
    #pragma unroll
    for (int mt = 0; mt < 4; ++mt)
      #pragma unroll
      for (int nt = 0; nt < 4; ++nt)
        acc[mt][nt] = (f32x4){0.f, 0.f, 0.f, 0.f};

    #pragma unroll
    for (int kt = 0; kt < KTW; ++kt){
      const int kg = (w*KTW + kt) * 32;
      #pragma unroll
      for (int mt = 0; mt < 4; ++mt){
        const int row = mt*16 + arow;   // batch row
        short8 a;
        if (kg < KX){
          a = *(const short8*)(xab + ((size_t)(row*T + t))*KX + (kg + kgrp));
        } else {
          const unsigned long long* hp = (const unsigned long long*)
              (hb + (size_t)par*64*U + (size_t)row*U + (kg - KX + kgrp));
          ulonglong2 u;
          u.x = __hip_atomic_load(hp,     __ATOMIC_RELAXED, __HIP_MEMORY_SCOPE_AGENT);
          u.y = __hip_atomic_load(hp + 1, __ATOMIC_RELAXED, __HIP_MEMORY_SCOPE_AGENT);
          a = __builtin_bit_cast(short8, u);
        }
        #pragma unroll
        for (int nt = 0; nt < 4; ++nt)
          acc[mt][nt] = __builtin_amdgcn_mfma_f32_16x16x32_bf16(a, bfr[kt][nt], acc[mt][nt], 0, 0, 0);
      }
    }

    // D-frag: col = lane&15 (zcol), rows = rquad..rquad+3 -> contiguous b128
    #pragma unroll
    for (int mt = 0; mt < 4; ++mt)
      #pragma unroll
      for (int nt = 0; nt < 4; ++nt)
        *(f32x4*)&part[w][nt*16 + arow][mt*16 + rquad] = acc[mt][nt];

    __syncthreads();

    // gate phase: reduce 4 wave partials; thread owns unit u_l, rows rb..rb+3
    f32x4 zg[4];
    #pragma unroll
    for (int g = 0; g < 4; ++g){
      const int cb = g*16 + u_l;
      f32x4 v = *(const f32x4*)&part[0][cb][rb];
      #pragma unroll
      for (int ww = 1; ww < 4; ++ww)
        v += *(const f32x4*)&part[ww][cb][rb];
      zg[g] = v;
    }

    #pragma unroll
    for (int r = 0; r < 4; ++r){
      float ig = sigm (zg[0][r] + bz[0]);
      float fg = sigm (zg[1][r] + bz[1]);
      float gg = tanh_(zg[2][r] + bz[2]);
      float og = sigm (zg[3][r] + bz[3]);
      float cn = fg * c[r] + ig * gg;
      float hn = og * tanh_(cn);
      bool m  = (t < sz[r]);
      c[r] = m ? cn : c[r];
      float h = m ? hn : hreg[r];
      hreg[r] = h;
      // write-through agent-scope atomic store: visible at coherence point
      __hip_atomic_store(&hb[(size_t)(par ^ 1)*64*U + (size_t)(rb + r)*U + ug],
                         (unsigned short)f2bf(h),
                         __ATOMIC_RELAXED, __HIP_MEMORY_SCOPE_AGENT);
      outp[((size_t)(rb + r)*T + t)*U + ug] = h;   // plain cached store
    }

    if (s != T - 1){
      __syncthreads();   // drains every wave's vmcnt: h atomic stores are at coherence point
      if (tid == 0)
        __hip_atomic_store(&flg[wg*32], (unsigned)(s + 1),
                           __ATOMIC_RELAXED, __HIP_MEMORY_SCOPE_AGENT);
      // every wave polls independently (no trailing barrier needed:
      // LDS reuse is fenced by the pre-flag __syncthreads)
      const unsigned tgt = (unsigned)(s + 1);
      for (;;){
        unsigned v = (lane < WGS)
          ? __hip_atomic_load(&flg[lane*32], __ATOMIC_RELAXED, __HIP_MEMORY_SCOPE_AGENT)
          : tgt;
        if (__all(v >= tgt)) break;
        __builtin_amdgcn_s_sleep(1);
      }
      __builtin_amdgcn_sched_barrier(0);
    }
  }
}

// ---------------- launch ----------------

extern "C" void kernel_launch(void* const* d_in, const int* in_sizes, int n_in,
                              void* d_out, int out_size, void* d_ws, size_t ws_size,
                              hipStream_t stream){
  const float* x      = (const float*)d_in[0];
  const int*   sizes  = (const int*)  d_in[1];
  const float* enc_kf = (const float*)d_in[2];
  const float* enc_rf = (const float*)d_in[3];
  const float* enc_bf = (const float*)d_in[4];
  const float* enc_kb = (const float*)d_in[5];
  const float* enc_rb = (const float*)d_in[6];
  const float* enc_bb = (const float*)d_in[7];
  const float* dec_kf = (const float*)d_in[8];
  const float* dec_rf = (const float*)d_in[9];
  const float* dec_bf = (const float*)d_in[10];
  const float* dec_kb = (const float*)d_in[11];
  const float* dec_rb = (const float*)d_in[12];
  const float* dec_bb = (const float*)d_in[13];
  float* out = (float*)d_out;
  char*  ws  = (char*)d_ws;

  const size_t o_xbf   = 0;                        // 33,554,432  x bf16 [64][512][512]
  const size_t o_esum  = o_xbf   + 33554432ull;    // 16,777,216  enc fwd+bwd sum bf16
  const size_t o_pBe   = o_esum  + 16777216ull;    //  3,145,728  packed enc [k;r]
  const size_t o_pBd   = o_pBe   + 3145728ull;     //  6,291,456  packed dec [k;r]
  const size_t o_hfe   = o_pBd   + 6291456ull;     // 33,554,432  enc fwd h f32
  const size_t o_hbe   = o_hfe   + 33554432ull;    // 33,554,432  enc bwd h f32
  const size_t o_hbd   = o_hbe   + 33554432ull;    // 67,108,864  dec bwd h f32
  const size_t o_hbufe = o_hbd   + 67108864ull;    //    131,072  enc h exchange
  const size_t o_hbufd = o_hbufe + 131072ull;      //    262,144  dec h exchange
  const size_t o_flge  = o_hbufd + 262144ull;      //      4,096  enc flags
  const size_t o_flgd  = o_flge  + 4096ull;        //      8,192  dec flags
  const size_t total   = o_flgd  + 8192ull;
  if (ws_size < total) return;

  unsigned short* xbf   = (unsigned short*)(ws + o_xbf);
  unsigned short* esum  = (unsigned short*)(ws + o_esum);
  unsigned short* pBe   = (unsigned short*)(ws + o_pBe);
  unsigned short* pBd   = (unsigned short*)(ws + o_pBd);
  float*          hfe   = (float*)(ws + o_hfe);
  float*          hbe   = (float*)(ws + o_hbe);
  float*          hbd   = (float*)(ws + o_hbd);
  unsigned short* hbufe = (unsigned short*)(ws + o_hbufe);
  unsigned short* hbufd = (unsigned short*)(ws + o_hbufd);
  unsigned int*   flge  = (unsigned int*)(ws + o_flge);
  unsigned int*   flgd  = (unsigned int*)(ws + o_flgd);

  // zero h exchange buffers + flags (every call -> deterministic replays)
  hipMemsetAsync(ws + o_hbufe, 0, 131072ull + 262144ull + 4096ull + 8192ull, stream);

  // x -> bf16
  k_f32_to_bf16<<<2048, 256, 0, stream>>>(x, xbf, 64*512*512);

  // pack weights
  k_pack<<<2048, 256, 0, stream>>>(enc_kf, enc_rf, enc_kb, enc_rb, pBe, 786432, 512, 256);
  k_pack<<<2048, 256, 0, stream>>>(dec_kf, dec_rf, dec_kb, dec_rb, pBd, 1572864, 256, 512);

  // encoder bilstm (fwd group 16 WGs + bwd group 16 WGs)
  lstm_rec<512, 256, 16><<<32, 256, 0, stream>>>(xbf, pBe, enc_bf, enc_bb, sizes,
                                                 hbufe, flge, hfe, hbe);
  // enc_sum = bf16(hf + hb)
  k_add_bf16<<<2048, 256, 0, stream>>>(hfe, hbe, esum, 64*512*256);

  // decoder bilstm: fwd writes d_out directly, bwd to ws
  lstm_rec<256, 512, 32><<<64, 256, 0, stream>>>(esum, pBd, dec_bf, dec_bb, sizes,
                                                 hbufd, flgd, out, hbd);
  // d_out += dec bwd
  k_add_f32<<<2048, 256, 0, stream>>>(out, hbd, 64*512*512);
}

// Round 5
// 5580.193 us; speedup vs baseline: 1.8649x; 1.5660x over previous
//
#include <hip/hip_runtime.h>
#include <stdint.h>

using short8 = __attribute__((ext_vector_type(8))) short;
using f32x4  = __attribute__((ext_vector_type(4))) float;

#define DEV static __device__ __forceinline__

DEV unsigned short f2bf(float f){
  unsigned u = __builtin_bit_cast(unsigned, f);
  u = (u + 0x7FFFu + ((u >> 16) & 1u)) >> 16;
  return (unsigned short)u;
}
DEV float sigm(float x){
  float e = __builtin_amdgcn_exp2f(-1.4426950408889634f * x);
  return __builtin_amdgcn_rcpf(1.0f + e);
}
DEV float tanh_(float x){
  float e = __builtin_amdgcn_exp2f(2.885390081777927f * x); // exp(2x)
  return 1.0f - 2.0f * __builtin_amdgcn_rcpf(e + 1.0f);
}

// ---------------- aux kernels ----------------

__global__ void k_f32_to_bf16(const float* __restrict__ in, unsigned short* __restrict__ out, int n){
  int stride = gridDim.x * blockDim.x * 4;
  for (int i = (blockIdx.x * blockDim.x + threadIdx.x) * 4; i < n; i += stride){
    float4 v = *(const float4*)(in + i);
    ushort4 o4;
    o4.x = f2bf(v.x); o4.y = f2bf(v.y); o4.z = f2bf(v.z); o4.w = f2bf(v.w);
    *(ushort4*)(out + i) = o4;
  }
}

__global__ void k_add_bf16(const float* __restrict__ a, const float* __restrict__ b,
                           unsigned short* __restrict__ out, int n){
  int stride = gridDim.x * blockDim.x * 4;
  for (int i = (blockIdx.x * blockDim.x + threadIdx.x) * 4; i < n; i += stride){
    float4 va = *(const float4*)(a + i);
    float4 vb = *(const float4*)(b + i);
    ushort4 o4;
    o4.x = f2bf(va.x + vb.x); o4.y = f2bf(va.y + vb.y);
    o4.z = f2bf(va.z + vb.z); o4.w = f2bf(va.w + vb.w);
    *(ushort4*)(out + i) = o4;
  }
}

__global__ void k_add_f32(float* __restrict__ o, const float* __restrict__ b, int n){
  int stride = gridDim.x * blockDim.x * 4;
  for (int i = (blockIdx.x * blockDim.x + threadIdx.x) * 4; i < n; i += stride){
    float4 vo = *(const float4*)(o + i);
    float4 vb = *(const float4*)(b + i);
    vo.x += vb.x; vo.y += vb.y; vo.z += vb.z; vo.w += vb.w;
    *(float4*)(o + i) = vo;
  }
}

// Pack [k; r] (f32, [K, 4U] each, K split KX|U) into per-(dir,wg,wave,ktile,ntile)
// MFMA B-fragment order: idx = ((((wg*4+w)*6+kt)*4+nt)*64+lane)*8+j
__global__ void k_pack(const float* __restrict__ k0, const float* __restrict__ r0,
                       const float* __restrict__ k1, const float* __restrict__ r1,
                       unsigned short* __restrict__ out, int E, int KX, int U){
  int n = 2 * E;
  int stride = gridDim.x * blockDim.x;
  for (int i = blockIdx.x * blockDim.x + threadIdx.x; i < n; i += stride){
    int d = i / E, r = i % E;
    const float* Km = d ? k1 : k0;
    const float* Rm = d ? r1 : r0;
    int j    = r & 7;  int q = r >> 3;
    int lane = q & 63; q >>= 6;
    int nt   = q & 3;  q >>= 2;
    int kt   = q % 6;  q /= 6;
    int w    = q & 3;  int wg = q >> 2;
    int k    = (w*6 + kt)*32 + ((lane >> 4) << 3) + j;
    int col  = nt * U + wg*16 + (lane & 15);   // gate-major global column
    float v  = (k < KX) ? Km[(size_t)k * (4*U) + col]
                        : Rm[(size_t)(k - KX) * (4*U) + col];
    out[i] = f2bf(v);
  }
}

// ---------------- persistent recurrence kernel ----------------
// Step structure (latency-optimized):
//   x-MFMAs (from prefetched regs)  -> h-waves poll single counter ->
//   h LLC loads + h-MFMAs -> LDS partials -> sync -> gate -> h atomic store
//   -> sync -> tid0 atomicAdd(counter) -> out store (overlaps) ->
//   x(t+1) register prefetch (overlaps next wait).
// Pure-x waves (low K-split ranks) never poll; they wait at the HW barrier.
// h exchange: relaxed agent-scope atomics (write-through / LLC-read), no
// cache maintenance ops anywhere.
template<int KX, int U, int WGS>
__global__ __launch_bounds__(256, 1)
void lstm_rec(const unsigned short* __restrict__ xab,    // [64][512][KX] bf16
              const unsigned short* __restrict__ packedB,
              const float* __restrict__ bias_f,
              const float* __restrict__ bias_b,
              const int*   __restrict__ sizes,
              unsigned short* __restrict__ hbuf,         // [2 dirs][2][64][U] bf16
              unsigned int*  __restrict__ counters,      // [2 dirs][32]
              float* __restrict__ out_f,                 // [64][512][U]
              float* __restrict__ out_b)
{
  constexpr int KTW = 6;               // (KX+U)/32/4 ktiles per wave
  constexpr int T   = 512;

  const int tid  = threadIdx.x;
  const int w    = tid >> 6;
  const int lane = tid & 63;
  const int dir  = (blockIdx.x >= WGS) ? 1 : 0;
  const int wg   = dir ? (int)blockIdx.x - WGS : (int)blockIdx.x;

  const unsigned short* pB = packedB + (size_t)dir * ((size_t)WGS*4*KTW*4*512)
                                     + (size_t)((wg*4 + w)*KTW)*4*512;
  unsigned short* hb  = hbuf + (size_t)dir * (2*64*U);
  unsigned int*   cnt = counters + dir * 32;
  const float* bias = dir ? bias_b : bias_f;
  float* outp       = dir ? out_b : out_f;

  // does this wave own any h-ktile? (tiles are fully x or fully h: KX%32==0)
  const bool has_h = ((w*KTW + KTW - 1) * 32) >= KX;

  // preload B fragments (step-invariant): 96 VGPRs
  short8 bfr[KTW][4];
  #pragma unroll
  for (int kt = 0; kt < KTW; ++kt)
    #pragma unroll
    for (int nt = 0; nt < 4; ++nt)
      bfr[kt][nt] = *(const short8*)(pB + ((kt*4 + nt)*512) + lane*8);

  // gate-phase ownership: unit u_l (0..15), rows rb..rb+3
  const int u_l = tid & 15;
  const int rb  = (tid >> 4) * 4;
  const int ug  = wg*16 + u_l;
  float bz[4]; int sz[4];
  #pragma unroll
  for (int g = 0; g < 4; ++g) bz[g] = bias[g*U + ug];
  #pragma unroll
  for (int r = 0; r < 4; ++r) sz[r] = sizes[rb + r];
  float c[4]    = {0.f,0.f,0.f,0.f};
  float hreg[4] = {0.f,0.f,0.f,0.f};

  // [wave][zcol 64][row 64 + pad]; write (D-frag) and read (gate) both b128
  __shared__ float part[4][64][68];

  const int arow  = lane & 15;         // A-frag row / D-frag col within tile
  const int kgrp  = (lane >> 4) * 8;   // A-frag k offset within ktile
  const int rquad = (lane >> 4) * 4;   // D-frag row base

  // A-fragment register file; x slots prefetched one step ahead
  short8 areg[KTW][4];
  {
    const int t0 = dir ? T - 1 : 0;
    #pragma unroll
    for (int kt = 0; kt < KTW; ++kt){
      const int kg = (w*KTW + kt) * 32;
      if (kg < KX){
        #pragma unroll
        for (int mt = 0; mt < 4; ++mt)
          areg[kt][mt] = *(const short8*)(xab + ((size_t)((mt*16 + arow)*T + t0))*KX + (kg + kgrp));
      }
    }
  }

  for (int s = 0; s < T; ++s){
    const int t   = dir ? (T - 1 - s) : s;
    const int par = s & 1;

    f32x4 acc[4][4];
    #pragma unroll
    for (int mt = 0; mt < 4; ++mt)
      #pragma unroll
      for (int nt = 0; nt < 4; ++nt)
        acc[mt][nt] = (f32x4){0.f, 0.f, 0.f, 0.f};

    // ---- x-part MFMAs (independent of other WGs) ----
    #pragma unroll
    for (int kt = 0; kt < KTW; ++kt){
      const int kg = (w*KTW + kt) * 32;
      if (kg < KX){
        #pragma unroll
        for (int mt = 0; mt < 4; ++mt)
          #pragma unroll
          for (int nt = 0; nt < 4; ++nt)
            acc[mt][nt] = __builtin_amdgcn_mfma_f32_16x16x32_bf16(areg[kt][mt], bfr[kt][nt], acc[mt][nt], 0, 0, 0);
      }
    }

    if (s > 0){
      // ---- h-waves: wait for all WGs to have published h(s) ----
      if (has_h){
        const unsigned tgt = (unsigned)WGS * (unsigned)s;
        for (;;){
          unsigned v = __hip_atomic_load(cnt, __ATOMIC_RELAXED, __HIP_MEMORY_SCOPE_AGENT);
          if (v >= tgt) break;
          __builtin_amdgcn_s_sleep(1);
        }
        __builtin_amdgcn_sched_barrier(0);
        // ---- h loads (LLC) ----
        #pragma unroll
        for (int kt = 0; kt < KTW; ++kt){
          const int kg = (w*KTW + kt) * 32;
          if (kg >= KX){
            #pragma unroll
            for (int mt = 0; mt < 4; ++mt){
              const unsigned long long* hp = (const unsigned long long*)
                  (hb + (size_t)par*64*U + (size_t)(mt*16 + arow)*U + (kg - KX + kgrp));
              ulonglong2 u;
              u.x = __hip_atomic_load(hp,     __ATOMIC_RELAXED, __HIP_MEMORY_SCOPE_AGENT);
              u.y = __hip_atomic_load(hp + 1, __ATOMIC_RELAXED, __HIP_MEMORY_SCOPE_AGENT);
              areg[kt][mt] = __builtin_bit_cast(short8, u);
            }
          }
        }
        // ---- h-part MFMAs ----
        #pragma unroll
        for (int kt = 0; kt < KTW; ++kt){
          const int kg = (w*KTW + kt) * 32;
          if (kg >= KX){
            #pragma unroll
            for (int mt = 0; mt < 4; ++mt)
              #pragma unroll
              for (int nt = 0; nt < 4; ++nt)
                acc[mt][nt] = __builtin_amdgcn_mfma_f32_16x16x32_bf16(areg[kt][mt], bfr[kt][nt], acc[mt][nt], 0, 0, 0);
          }
        }
      }
    }

    // D-frag scatter: col = lane&15 (zcol), rows rquad..rquad+3 -> b128
    #pragma unroll
    for (int mt = 0; mt < 4; ++mt)
      #pragma unroll
      for (int nt = 0; nt < 4; ++nt)
        *(f32x4*)&part[w][nt*16 + arow][mt*16 + rquad] = acc[mt][nt];

    __syncthreads();

    // gate phase: reduce 4 wave partials; thread owns unit u_l, rows rb..rb+3
    f32x4 zg[4];
    #pragma unroll
    for (int g = 0; g < 4; ++g){
      const int cb = g*16 + u_l;
      f32x4 v = *(const f32x4*)&part[0][cb][rb];
      #pragma unroll
      for (int ww = 1; ww < 4; ++ww)
        v += *(const f32x4*)&part[ww][cb][rb];
      zg[g] = v;
    }

    #pragma unroll
    for (int r = 0; r < 4; ++r){
      float ig = sigm (zg[0][r] + bz[0]);
      float fg = sigm (zg[1][r] + bz[1]);
      float gg = tanh_(zg[2][r] + bz[2]);
      float og = sigm (zg[3][r] + bz[3]);
      float cn = fg * c[r] + ig * gg;
      float hn = og * tanh_(cn);
      bool m  = (t < sz[r]);
      c[r] = m ? cn : c[r];
      float h = m ? hn : hreg[r];
      hreg[r] = h;
      // write-through agent-scope atomic store -> coherence point
      __hip_atomic_store(&hb[(size_t)(par ^ 1)*64*U + (size_t)(rb + r)*U + ug],
                         (unsigned short)f2bf(h),
                         __ATOMIC_RELAXED, __HIP_MEMORY_SCOPE_AGENT);
    }

    __syncthreads();   // drains every wave's vmcnt: h stores visible at LLC

    if (s != T - 1){
      if (tid == 0) atomicAdd(cnt, 1u);   // device-scope, fire-and-forget
    }

    // out store AFTER the publish: its HBM ack overlaps the next wait
    #pragma unroll
    for (int r = 0; r < 4; ++r)
      outp[((size_t)(rb + r)*T + t)*U + ug] = hreg[r];

    // x prefetch for next step: HBM latency absorbed into the wait
    if (s != T - 1){
      const int tn = dir ? t - 1 : t + 1;
      #pragma unroll
      for (int kt = 0; kt < KTW; ++kt){
        const int kg = (w*KTW + kt) * 32;
        if (kg < KX){
          #pragma unroll
          for (int mt = 0; mt < 4; ++mt)
            areg[kt][mt] = *(const short8*)(xab + ((size_t)((mt*16 + arow)*T + tn))*KX + (kg + kgrp));
        }
      }
    }
  }
}

// ---------------- launch ----------------

extern "C" void kernel_launch(void* const* d_in, const int* in_sizes, int n_in,
                              void* d_out, int out_size, void* d_ws, size_t ws_size,
                              hipStream_t stream){
  const float* x      = (const float*)d_in[0];
  const int*   sizes  = (const int*)  d_in[1];
  const float* enc_kf = (const float*)d_in[2];
  const float* enc_rf = (const float*)d_in[3];
  const float* enc_bf = (const float*)d_in[4];
  const float* enc_kb = (const float*)d_in[5];
  const float* enc_rb = (const float*)d_in[6];
  const float* enc_bb = (const float*)d_in[7];
  const float* dec_kf = (const float*)d_in[8];
  const float* dec_rf = (const float*)d_in[9];
  const float* dec_bf = (const float*)d_in[10];
  const float* dec_kb = (const float*)d_in[11];
  const float* dec_rb = (const float*)d_in[12];
  const float* dec_bb = (const float*)d_in[13];
  float* out = (float*)d_out;
  char*  ws  = (char*)d_ws;

  const size_t o_xbf   = 0;                        // 33,554,432  x bf16 [64][512][512]
  const size_t o_esum  = o_xbf   + 33554432ull;    // 16,777,216  enc fwd+bwd sum bf16
  const size_t o_pBe   = o_esum  + 16777216ull;    //  3,145,728  packed enc [k;r]
  const size_t o_pBd   = o_pBe   + 3145728ull;     //  6,291,456  packed dec [k;r]
  const size_t o_hfe   = o_pBd   + 6291456ull;     // 33,554,432  enc fwd h f32
  const size_t o_hbe   = o_hfe   + 33554432ull;    // 33,554,432  enc bwd h f32
  const size_t o_hbd   = o_hbe   + 33554432ull;    // 67,108,864  dec bwd h f32
  const size_t o_hbufe = o_hbd   + 67108864ull;    //    131,072  enc h exchange
  const size_t o_hbufd = o_hbufe + 131072ull;      //    262,144  dec h exchange
  const size_t o_cnte  = o_hbufd + 262144ull;      //      4,096  enc counters
  const size_t o_cntd  = o_cnte  + 4096ull;        //      4,096  dec counters
  const size_t total   = o_cntd  + 4096ull;
  if (ws_size < total) return;

  unsigned short* xbf   = (unsigned short*)(ws + o_xbf);
  unsigned short* esum  = (unsigned short*)(ws + o_esum);
  unsigned short* pBe   = (unsigned short*)(ws + o_pBe);
  unsigned short* pBd   = (unsigned short*)(ws + o_pBd);
  float*          hfe   = (float*)(ws + o_hfe);
  float*          hbe   = (float*)(ws + o_hbe);
  float*          hbd   = (float*)(ws + o_hbd);
  unsigned short* hbufe = (unsigned short*)(ws + o_hbufe);
  unsigned short* hbufd = (unsigned short*)(ws + o_hbufd);
  unsigned int*   cnte  = (unsigned int*)(ws + o_cnte);
  unsigned int*   cntd  = (unsigned int*)(ws + o_cntd);

  // zero counters every call (deterministic graph replays); h exchange needs
  // no init: step 0 never reads it, every later read is written at step s-1.
  hipMemsetAsync(ws + o_cnte, 0, 8192ull, stream);

  // x -> bf16
  k_f32_to_bf16<<<2048, 256, 0, stream>>>(x, xbf, 64*512*512);

  // pack weights
  k_pack<<<2048, 256, 0, stream>>>(enc_kf, enc_rf, enc_kb, enc_rb, pBe, 786432, 512, 256);
  k_pack<<<2048, 256, 0, stream>>>(dec_kf, dec_rf, dec_kb, dec_rb, pBd, 1572864, 256, 512);

  // encoder bilstm (fwd group 16 WGs + bwd group 16 WGs)
  lstm_rec<512, 256, 16><<<32, 256, 0, stream>>>(xbf, pBe, enc_bf, enc_bb, sizes,
                                                 hbufe, cnte, hfe, hbe);
  // enc_sum = bf16(hf + hb)
  k_add_bf16<<<2048, 256, 0, stream>>>(hfe, hbe, esum, 64*512*256);

  // decoder bilstm: fwd writes d_out directly, bwd to ws
  lstm_rec<256, 512, 32><<<64, 256, 0, stream>>>(esum, pBd, dec_bf, dec_bb, sizes,
                                                 hbufd, cntd, out, hbd);
  // d_out += dec bwd
  k_add_f32<<<2048, 256, 0, stream>>>(out, hbd, 64*512*512);
}